// Round 17
// baseline (100.427 us; speedup 1.0000x reference)
//
#include <hip/hip_runtime.h>
#include <hip/hip_fp16.h>

#define NBC 14
#define NAC 45
#define KF  52
#define RHO 0.05f
#define TT  4096
#define BB  64
#define CHC 64           // outputs per chain
#define WU  44           // warmup steps
#define NQUAD 16         // quads per batch (4 chains x 64 outputs = 256 per block)
#define NTW (WU + CHC)   // 108 steps
#define SPAN (WU + 4*CHC)// 300: xf range covers 4 chains
#define XPAD 304         // xf row stride (halfs), mult of 4
#define LOG2E 1.44269504f
#define XF_BYTES ((size_t)BB * NBC * TT * 2)

typedef __fp16 v2h __attribute__((ext_vector_type(2)));
typedef float  f2  __attribute__((ext_vector_type(2)));
typedef int    i2v __attribute__((ext_vector_type(2)));

__device__ __forceinline__ v2h bch(unsigned u) { return __builtin_bit_cast(v2h, u); }
__device__ __forceinline__ unsigned bcu(v2h h) { return __builtin_bit_cast(unsigned, h); }
__device__ __forceinline__ v2h pk2(float lo, float hi) {
#if __has_builtin(__builtin_amdgcn_cvt_pkrtz)
  return __builtin_bit_cast(v2h, __builtin_amdgcn_cvt_pkrtz(lo, hi));
#else
  v2h r; r[0] = (__fp16)lo; r[1] = (__fp16)hi; return r;
#endif
}
__device__ __forceinline__ v2h xsum16h(v2h v) {
#if __has_builtin(__builtin_amdgcn_permlane16_swap)
  i2v r = __builtin_amdgcn_permlane16_swap((int)bcu(v), (int)bcu(v), false, false);
  return bch((unsigned)r[0]) + bch((unsigned)r[1]);
#else
  return v + bch((unsigned)__builtin_amdgcn_ds_swizzle((int)bcu(v), (16 << 10) | 0x1f));
#endif
}
__device__ __forceinline__ v2h xsum32h(v2h v) {
#if __has_builtin(__builtin_amdgcn_permlane32_swap)
  i2v r = __builtin_amdgcn_permlane32_swap((int)bcu(v), (int)bcu(v), false, false);
  return bch((unsigned)r[0]) + bch((unsigned)r[1]);
#else
  return v + bch((unsigned)__shfl_xor((int)bcu(v), 32));
#endif
}
__device__ __forceinline__ float exp2_f(float x) {
#if __has_builtin(__builtin_amdgcn_exp2f)
  return __builtin_amdgcn_exp2f(x);
#else
  return exp2f(x);
#endif
}

// ---------------- conv pre-pass: xf[b][c][t] for all t ----------------
__global__ __launch_bounds__(256)
void conv_kernel(const float* __restrict__ x, const float* __restrict__ bck,
                 __half* __restrict__ xfg) {
  __shared__ float xs[256 + KF];
  const int tid  = threadIdx.x;
  const int b    = blockIdx.x >> 4;
  const int t0   = (blockIdx.x & 15) << 8;
  for (int i = tid; i < 256 + KF - 1; i += 256) {
    int gt = t0 - (KF - 1) + i;
    xs[i] = (gt >= 0) ? x[b * TT + gt] : 0.f;
  }
  __syncthreads();
  float acc[NBC];
#pragma unroll
  for (int c = 0; c < NBC; ++c) acc[c] = 0.f;
#pragma unroll 4
  for (int k = 0; k < KF; ++k) {
    float xv = xs[tid + k];
#pragma unroll
    for (int c = 0; c < NBC; ++c) acc[c] = fmaf(bck[c * KF + k], xv, acc[c]);
  }
#pragma unroll
  for (int c = 0; c < NBC; ++c)
    xfg[((size_t)b * NBC + c) * TT + t0 + tid] = __float2half(acc[c]);
}

// LDS pool (bytes):
//  [0,    8512)  xf fp16 [NBC][XPAD]
//  [8512, 8768)  acr1 u32 [64]   (entries 45..63 stay zero)
//  [8768, 9024)  acr2 u32 [64]
//  [9024, 9088)  relr1 u32 [16]  (entries 14,15 stay zero)
//  [9088, 9152)  relr2 u32 [16]
//  [9152,10560)  x slice f32 [352]  (in-kernel conv fallback only)
#define POOL_BYTES 10560

template<bool PRECONV>
__global__ __launch_bounds__(64)
void bcn_kernel(const float* __restrict__ x,
                const float* __restrict__ bck,
                const float* __restrict__ lss,
                const float* __restrict__ soff,
                const float* __restrict__ lbaw,
                const float* __restrict__ ltr,
                const float* __restrict__ ltd,
                const float* __restrict__ lass,
                const float* __restrict__ asoff,
                const float* __restrict__ labw,
                const float* __restrict__ oscale,
                const __half* __restrict__ xfg,
                float* __restrict__ out)
{
  __shared__ __align__(16) char pool[POOL_BYTES];
  __half*   xf_lds = (__half*)pool;                    // [NBC][XPAD]
  unsigned* acr1   = (unsigned*)(pool + 8512);
  unsigned* acr2   = (unsigned*)(pool + 8768);
  unsigned* relr1  = (unsigned*)(pool + 9024);
  unsigned* relr2  = (unsigned*)(pool + 9088);
  float*    x_lds  = (float*)(pool + 9152);            // conv fallback only

  const int lid   = threadIdx.x;
  const int c16   = lid & 15;
  const int q     = lid >> 4;
  const float rowm = (q & 1) ? 0.f : 1.f;   // rows 0,2: BCN; rows 1,3: LNR
  const int blk   = blockIdx.x;
  const int b     = blk >> 4;            // batch
  const int p     = blk & 15;            // quad index
  const int t0A   = p * (4 * CHC);
  const int t_begin = t0A - WU;

  if constexpr (PRECONV) {
    const __half* src = xfg + (size_t)b * NBC * TT;
    if (p == 0) {
      for (int e = lid; e < NBC * SPAN; e += 64) {
        int c = e / SPAN, i = e - c * SPAN;
        int gt = t_begin + i; if (gt < 0) gt = 0;   // chain-A warm garbage, reset later
        xf_lds[c * XPAD + i] = src[(size_t)c * TT + gt];
      }
    } else {
      for (int e = lid; e < NBC * (SPAN / 4); e += 64) {
        int c = e / (SPAN / 4), i = e - c * (SPAN / 4);
        uint2 v = *(const uint2*)(src + (size_t)c * TT + t_begin + 4 * i);
        *(uint2*)&xf_lds[c * XPAD + 4 * i] = v;
      }
    }
  } else {
    for (int i = lid; i < SPAN + KF - 1; i += 64) {
      int gt = t_begin - (KF - 1) + i;
      x_lds[i] = (gt >= 0) ? x[b * TT + gt] : 0.f;
    }
    __syncthreads();
    for (int ib = 0; ib < 5; ++ib) {
      int tau = lid + (ib << 6);
      if (tau < SPAN) {
        float acc[NBC];
#pragma unroll
        for (int c = 0; c < NBC; ++c) acc[c] = 0.f;
#pragma unroll 4
        for (int k = 0; k < KF; ++k) {
          float xv = x_lds[tau + k];
#pragma unroll
          for (int c = 0; c < NBC; ++c) acc[c] = fmaf(bck[c * KF + k], xv, acc[c]);
        }
#pragma unroll
        for (int c = 0; c < NBC; ++c) xf_lds[c * XPAD + tau] = __float2half(acc[c]);
      }
    }
    __syncthreads();
  }

  // ---- zero gather buffers ----
  if (lid < 64) { acr1[lid] = 0u; acr2[lid] = 0u; }
  if (lid < 16) { relr1[lid] = 0u; relr2[lid] = 0u; }

  // ---- per-lane parameters (shared by all 4 chains) ----
  float slope2 = 0.f, soff2 = 0.f, osc_c = 0.f;
  f2 poolP1; poolP1.x = 1.f; poolP1.y = 1.f;
  f2 poolP2; poolP2.x = 1.f; poolP2.y = 1.f;
  f2 SA; SA.x = 0.f; SA.y = 0.f;
  f2 SB; SB.x = 0.f; SB.y = 0.f;
  f2 SC; SC.x = 0.f; SC.y = 0.f;
  f2 SD; SD.x = 0.f; SD.y = 0.f;
  f2 rv2, cn2; rv2.x = rv2.y = cn2.x = cn2.y = 0.f;
  float Adrv2 = 0.f, Boff2 = 0.f;
  v2h wfbh[16];
  v2h wuh[NBC];
  f2 yst1[4], fst1[4], yst2[4], fst2[4];
  unsigned acst1[4], acst2[4];

#pragma unroll
  for (int j = 0; j < 16; ++j) wfbh[j] = pk2(0.f, 0.f);
#pragma unroll
  for (int c = 0; c < NBC; ++c) wuh[c] = pk2(0.f, 0.f);

  if (c16 < NBC) {
    float sl = expf(lss[c16]);
    slope2 = sl * LOG2E;
    soff2  = soff[c16] * sl * LOG2E;
    osc_c  = oscale[c16];
#pragma unroll
    for (int j = 0; j < 16; ++j) {
      int a = 16 * q + j;
      if (a < NAC) { float w = -expf(labw[c16 * NAC + a]); wfbh[j] = pk2(w, w); }
    }
  }
  if (lid < NAC) {
    float tr = expf(ltr[lid]);
    float td = expf(ltd[lid]);
    float a1 = 1.f / td;
    float gg = (td + tr) / (td * tr);
    rv2.x = expf(-a1 * 0.015625f);  rv2.y = expf(-gg * 0.015625f);
    cn2.x = expf(-a1 * 0.003125f);  cn2.y = expf(-gg * 0.003125f);
    float nrm = 0.f;
    for (int k = 0; k < KF; ++k) {
      float kt = 0.8f - (float)k * 0.015625f;
      float d = expf(-a1 * kt) - expf(-gg * kt);
      nrm = fmaf(d, d, nrm);
    }
    float inorm  = 1.f / sqrtf(nrm);
    float aslope = expf(lass[lid]);
    Adrv2 = aslope * inorm * LOG2E;
    Boff2 = aslope * asoff[lid] * LOG2E;
#pragma unroll
    for (int c = 0; c < NBC; ++c) {
      float w = expf(lbaw[lid * NBC + c]);
      wuh[c] = pk2(w, w);
    }
  }

  float* yb  = out;
  float* fbp = out + (size_t)BB * TT * NBC;
  float* acp = out + 2 * (size_t)BB * TT * NBC;
  float* ylp = out + 2 * (size_t)BB * TT * NBC + (size_t)BB * TT * NAC;

  __syncthreads();

  // ---- one quad-chain step: two independent dual-chain bodies (ILP) ----
  auto step = [&](int slot4, float xA, float xB, float xC, float xD, bool emit)
      __attribute__((always_inline)) {
    // AC sigmoids, all 4 chains
    float mzA = fmaf(-Adrv2, SA.x - SA.y, Boff2);
    float mzB = fmaf(-Adrv2, SB.x - SB.y, Boff2);
    float mzC = fmaf(-Adrv2, SC.x - SC.y, Boff2);
    float mzD = fmaf(-Adrv2, SD.x - SD.y, Boff2);
    float acA = __fdividef(1.f, 1.f + exp2_f(mzA));
    float acB = __fdividef(1.f, 1.f + exp2_f(mzB));
    float acC = __fdividef(1.f, 1.f + exp2_f(mzC));
    float acD = __fdividef(1.f, 1.f + exp2_f(mzD));
    if (lid < NAC) { acr1[lid] = bcu(pk2(acA, acB)); acr2[lid] = bcu(pk2(acC, acD)); }

    // fb gathers (independent pair bodies)
    const uint4* ab1 = (const uint4*)(acr1 + (q << 4));
    const uint4* ab2 = (const uint4*)(acr2 + (q << 4));
    uint4 P0 = ab1[0], P1 = ab1[1], P2 = ab1[2], P3 = ab1[3];
    uint4 Q0 = ab2[0], Q1 = ab2[1], Q2 = ab2[2], Q3 = ab2[3];
    v2h g0 = wfbh[0] * bch(P0.x), g1 = wfbh[1] * bch(P0.y);
    v2h e0 = wfbh[0] * bch(Q0.x), e1 = wfbh[1] * bch(Q0.y);
    g0 += wfbh[2]  * bch(P0.z);  g1 += wfbh[3]  * bch(P0.w);
    e0 += wfbh[2]  * bch(Q0.z);  e1 += wfbh[3]  * bch(Q0.w);
    g0 += wfbh[4]  * bch(P1.x);  g1 += wfbh[5]  * bch(P1.y);
    e0 += wfbh[4]  * bch(Q1.x);  e1 += wfbh[5]  * bch(Q1.y);
    g0 += wfbh[6]  * bch(P1.z);  g1 += wfbh[7]  * bch(P1.w);
    e0 += wfbh[6]  * bch(Q1.z);  e1 += wfbh[7]  * bch(Q1.w);
    g0 += wfbh[8]  * bch(P2.x);  g1 += wfbh[9]  * bch(P2.y);
    e0 += wfbh[8]  * bch(Q2.x);  e1 += wfbh[9]  * bch(Q2.y);
    g0 += wfbh[10] * bch(P2.z);  g1 += wfbh[11] * bch(P2.w);
    e0 += wfbh[10] * bch(Q2.z);  e1 += wfbh[11] * bch(Q2.w);
    g0 += wfbh[12] * bch(P3.x);  g1 += wfbh[13] * bch(P3.y);
    e0 += wfbh[12] * bch(Q3.x);  e1 += wfbh[13] * bch(Q3.y);
    g0 += wfbh[14] * bch(P3.z);  g1 += wfbh[15] * bch(P3.w);
    e0 += wfbh[14] * bch(Q3.z);  e1 += wfbh[15] * bch(Q3.w);
    v2h gs1 = xsum32h(xsum16h(g0 + g1));
    v2h gs2 = xsum32h(xsum16h(e0 + e1));
    float fbA = (float)gs1[0], fbB = (float)gs1[1];
    float fbC = (float)gs2[0], fbD = (float)gs2[1];

    // role-fused BC/LNR sigmoids
    float mA = fmaf(-slope2, fmaf(rowm, fbA, xA), soff2);
    float mB = fmaf(-slope2, fmaf(rowm, fbB, xB), soff2);
    float mC = fmaf(-slope2, fmaf(rowm, fbC, xC), soff2);
    float mD = fmaf(-slope2, fmaf(rowm, fbD, xD), soff2);
    f2 pv1, pv2;
    pv1.x = __fdividef(1.f, 1.f + exp2_f(mA));
    pv1.y = __fdividef(1.f, 1.f + exp2_f(mB));
    pv2.x = __fdividef(1.f, 1.f + exp2_f(mC));
    pv2.y = __fdividef(1.f, 1.f + exp2_f(mD));
    f2 p21 = poolP1 * (1.f - RHO) + RHO;
    f2 p22 = poolP2 * (1.f - RHO) + RHO;
    f2 rel1 = pv1 * p21, rel2 = pv2 * p22;
    poolP1 = p21 - rel1;  poolP2 = p22 - rel2;
    if (lid < NBC) { relr1[lid] = bcu(pk2(rel1.x, rel1.y));
                     relr2[lid] = bcu(pk2(rel2.x, rel2.y)); }
    if (emit) {
      yst1[slot4] = rel1 * osc_c;  yst2[slot4] = rel2 * osc_c;
      f2 t1; t1.x = fbA; t1.y = fbB; fst1[slot4] = t1;
      f2 t2; t2.x = fbC; t2.y = fbD; fst2[slot4] = t2;
      acst1[slot4] = bcu(pk2(acA, acB));
      acst2[slot4] = bcu(pk2(acC, acD));
    }

    // u gathers
    const uint4* rb1 = (const uint4*)relr1;
    const uint4* rb2 = (const uint4*)relr2;
    uint4 R0 = rb1[0], R1 = rb1[1], R2 = rb1[2], R3 = rb1[3];
    uint4 T0 = rb2[0], T1 = rb2[1], T2 = rb2[2], T3 = rb2[3];
    v2h h0 = wuh[0] * bch(R0.x), h1 = wuh[1] * bch(R0.y);
    v2h k0 = wuh[0] * bch(T0.x), k1 = wuh[1] * bch(T0.y);
    h0 += wuh[2]  * bch(R0.z);  h1 += wuh[3]  * bch(R0.w);
    k0 += wuh[2]  * bch(T0.z);  k1 += wuh[3]  * bch(T0.w);
    h0 += wuh[4]  * bch(R1.x);  h1 += wuh[5]  * bch(R1.y);
    k0 += wuh[4]  * bch(T1.x);  k1 += wuh[5]  * bch(T1.y);
    h0 += wuh[6]  * bch(R1.z);  h1 += wuh[7]  * bch(R1.w);
    k0 += wuh[6]  * bch(T1.z);  k1 += wuh[7]  * bch(T1.w);
    h0 += wuh[8]  * bch(R2.x);  h1 += wuh[9]  * bch(R2.y);
    k0 += wuh[8]  * bch(T2.x);  k1 += wuh[9]  * bch(T2.y);
    h0 += wuh[10] * bch(R2.z);  h1 += wuh[11] * bch(R2.w);
    k0 += wuh[10] * bch(T2.z);  k1 += wuh[11] * bch(T2.w);
    h0 += wuh[12] * bch(R3.x);  h1 += wuh[13] * bch(R3.y);
    k0 += wuh[12] * bch(T3.x);  k1 += wuh[13] * bch(T3.y);
    v2h uh1 = h0 + h1, uh2 = k0 + k1;
    SA = SA * rv2 + cn2 * (float)uh1[0];
    SB = SB * rv2 + cn2 * (float)uh1[1];
    SC = SC * rv2 + cn2 * (float)uh2[0];
    SD = SD * rv2 + cn2 * (float)uh2[1];
  };

  auto group = [&](int s4, bool emit) __attribute__((always_inline)) {
    uint2 xa = *(const uint2*)&xf_lds[c16 * XPAD + s4];
    uint2 xb = *(const uint2*)&xf_lds[c16 * XPAD + s4 + CHC];
    uint2 xc = *(const uint2*)&xf_lds[c16 * XPAD + s4 + 2 * CHC];
    uint2 xd = *(const uint2*)&xf_lds[c16 * XPAD + s4 + 3 * CHC];
    v2h a01 = bch(xa.x), a23 = bch(xa.y);
    v2h b01 = bch(xb.x), b23 = bch(xb.y);
    v2h c01 = bch(xc.x), c23 = bch(xc.y);
    v2h d01 = bch(xd.x), d23 = bch(xd.y);
    step(0, (float)a01[0], (float)b01[0], (float)c01[0], (float)d01[0], emit);
    step(1, (float)a01[1], (float)b01[1], (float)c01[1], (float)d01[1], emit);
    step(2, (float)a23[0], (float)b23[0], (float)c23[0], (float)d23[0], emit);
    step(3, (float)a23[1], (float)b23[1], (float)c23[1], (float)d23[1], emit);
  };

  // ---- warm phase ----
  for (int s4 = 0; s4 < WU; s4 += 4) group(s4, false);

  // chunk-0 exact start: reset chain A state (true history is empty)
  if (p == 0) {
    SA.x = 0.f; SA.y = 0.f;
    poolP1.x = 1.f;
  }

  // ---- emit phase ----
  for (int s4 = WU; s4 < NTW; s4 += 4) {
    group(s4, true);

    int tg = t0A + (s4 - WU);
    size_t base = (size_t)b * TT + tg;
    if (lid < NBC) {                       // row 0: y_bcn + fb, 4 chains
      size_t ob = base * NBC + lid;
#pragma unroll
      for (int sl = 0; sl < 4; ++sl) {
        yb [ob + sl * NBC]                         = yst1[sl].x;
        yb [ob + (size_t)CHC * NBC + sl * NBC]     = yst1[sl].y;
        yb [ob + 2 * (size_t)CHC * NBC + sl * NBC] = yst2[sl].x;
        yb [ob + 3 * (size_t)CHC * NBC + sl * NBC] = yst2[sl].y;
        fbp[ob + sl * NBC]                         = fst1[sl].x;
        fbp[ob + (size_t)CHC * NBC + sl * NBC]     = fst1[sl].y;
        fbp[ob + 2 * (size_t)CHC * NBC + sl * NBC] = fst2[sl].x;
        fbp[ob + 3 * (size_t)CHC * NBC + sl * NBC] = fst2[sl].y;
      }
    } else if (lid >= 16 && lid < 16 + NBC) {  // row 1: y_lnr, 4 chains
      size_t ob = base * NBC + (lid - 16);
#pragma unroll
      for (int sl = 0; sl < 4; ++sl) {
        ylp[ob + sl * NBC]                         = yst1[sl].x;
        ylp[ob + (size_t)CHC * NBC + sl * NBC]     = yst1[sl].y;
        ylp[ob + 2 * (size_t)CHC * NBC + sl * NBC] = yst2[sl].x;
        ylp[ob + 3 * (size_t)CHC * NBC + sl * NBC] = yst2[sl].y;
      }
    }
    if (lid < NAC) {
      size_t oa = base * NAC + lid;
#pragma unroll
      for (int sl = 0; sl < 4; ++sl) {
        v2h h1 = bch(acst1[sl]);
        v2h h2 = bch(acst2[sl]);
        acp[oa + sl * NAC]                         = (float)h1[0];
        acp[oa + (size_t)CHC * NAC + sl * NAC]     = (float)h1[1];
        acp[oa + 2 * (size_t)CHC * NAC + sl * NAC] = (float)h2[0];
        acp[oa + 3 * (size_t)CHC * NAC + sl * NAC] = (float)h2[1];
      }
    }
  }
}

extern "C" void kernel_launch(void* const* d_in, const int* in_sizes, int n_in,
                              void* d_out, int out_size, void* d_ws, size_t ws_size,
                              hipStream_t stream) {
  (void)in_sizes; (void)n_in; (void)out_size;
  const float* x    = (const float*)d_in[0];
  const float* bck  = (const float*)d_in[1];
  if (ws_size >= XF_BYTES) {
    __half* xfg = (__half*)d_ws;
    conv_kernel<<<dim3(BB * 16), dim3(256), 0, stream>>>(x, bck, xfg);
    bcn_kernel<true><<<dim3(BB * NQUAD), dim3(64), 0, stream>>>(
        x, bck, (const float*)d_in[2], (const float*)d_in[3], (const float*)d_in[4],
        (const float*)d_in[5], (const float*)d_in[6], (const float*)d_in[7],
        (const float*)d_in[8], (const float*)d_in[9], (const float*)d_in[10],
        xfg, (float*)d_out);
  } else {
    bcn_kernel<false><<<dim3(BB * NQUAD), dim3(64), 0, stream>>>(
        x, bck, (const float*)d_in[2], (const float*)d_in[3], (const float*)d_in[4],
        (const float*)d_in[5], (const float*)d_in[6], (const float*)d_in[7],
        (const float*)d_in[8], (const float*)d_in[9], (const float*)d_in[10],
        (const __half*)nullptr, (float*)d_out);
  }
}

// Round 18
// 92.741 us; speedup vs baseline: 1.0829x; 1.0829x over previous
//
#include <hip/hip_runtime.h>
#include <hip/hip_fp16.h>

#define NBC 14
#define NAC 45
#define KF  52
#define RHO 0.05f
#define TT  4096
#define BB  64
#define CHC 64           // outputs per chain
#define WU  44           // warmup steps
#define NPAIR 32         // chunk pairs per batch
#define NTW (WU + CHC)   // 108 steps per chain
#define SPAN (WU + 2*CHC)// 172: xf range covers both chains
#define XPAD 176         // xf row stride (halfs), mult of 4
#define LOG2E 1.44269504f
#define XF_BYTES ((size_t)BB * NBC * TT * 2)

typedef float f2 __attribute__((ext_vector_type(2)));
typedef int   i2v __attribute__((ext_vector_type(2)));

__device__ __forceinline__ __half2 bch(unsigned u) { return __builtin_bit_cast(__half2, u); }
__device__ __forceinline__ unsigned bcu(__half2 h) { return __builtin_bit_cast(unsigned, h); }
__device__ __forceinline__ __half2 pk2(float lo, float hi) {
  return __floats2half2_rn(lo, hi);
}
__device__ __forceinline__ __half2 xsum16h(__half2 v) {
#if __has_builtin(__builtin_amdgcn_permlane16_swap)
  i2v r = __builtin_amdgcn_permlane16_swap((int)bcu(v), (int)bcu(v), false, false);
  return __hadd2(bch((unsigned)r[0]), bch((unsigned)r[1]));
#else
  return __hadd2(v, bch((unsigned)__builtin_amdgcn_ds_swizzle((int)bcu(v), (16 << 10) | 0x1f)));
#endif
}
__device__ __forceinline__ __half2 xsum32h(__half2 v) {
#if __has_builtin(__builtin_amdgcn_permlane32_swap)
  i2v r = __builtin_amdgcn_permlane32_swap((int)bcu(v), (int)bcu(v), false, false);
  return __hadd2(bch((unsigned)r[0]), bch((unsigned)r[1]));
#else
  return __hadd2(v, bch((unsigned)__shfl_xor((int)bcu(v), 32)));
#endif
}
__device__ __forceinline__ float exp2_f(float x) {
#if __has_builtin(__builtin_amdgcn_exp2f)
  return __builtin_amdgcn_exp2f(x);
#else
  return exp2f(x);
#endif
}

// ---------------- conv pre-pass: xf[b][c][t] for all t ----------------
__global__ __launch_bounds__(256)
void conv_kernel(const float* __restrict__ x, const float* __restrict__ bck,
                 __half* __restrict__ xfg) {
  __shared__ float xs[256 + KF];
  const int tid  = threadIdx.x;
  const int b    = blockIdx.x >> 4;
  const int t0   = (blockIdx.x & 15) << 8;
  for (int i = tid; i < 256 + KF - 1; i += 256) {
    int gt = t0 - (KF - 1) + i;
    xs[i] = (gt >= 0) ? x[b * TT + gt] : 0.f;
  }
  __syncthreads();
  float acc[NBC];
#pragma unroll
  for (int c = 0; c < NBC; ++c) acc[c] = 0.f;
#pragma unroll 4
  for (int k = 0; k < KF; ++k) {
    float xv = xs[tid + k];
#pragma unroll
    for (int c = 0; c < NBC; ++c) acc[c] = fmaf(bck[c * KF + k], xv, acc[c]);
  }
#pragma unroll
  for (int c = 0; c < NBC; ++c)
    xfg[((size_t)b * NBC + c) * TT + t0 + tid] = __float2half(acc[c]);
}

// LDS pool (bytes):
//  [0,    4928)  xf fp16 [NBC][XPAD]
//  [4928, 5184)  acr u32 [64]   (entries 45..63 stay zero; 16B aligned)
//  [5184, 5248)  relr u32 [16]  (entries 14,15 stay zero)
//  [5248, 6144)  x slice f32 [224]  (in-kernel conv fallback only)
#define POOL_BYTES 6144

template<bool PRECONV>
__global__ __launch_bounds__(64)
void bcn_kernel(const float* __restrict__ x,
                const float* __restrict__ bck,
                const float* __restrict__ lss,
                const float* __restrict__ soff,
                const float* __restrict__ lbaw,
                const float* __restrict__ ltr,
                const float* __restrict__ ltd,
                const float* __restrict__ lass,
                const float* __restrict__ asoff,
                const float* __restrict__ labw,
                const float* __restrict__ oscale,
                const __half* __restrict__ xfg,
                float* __restrict__ out)
{
  __shared__ __align__(16) char pool[POOL_BYTES];
  __half*   xf_lds = (__half*)pool;                    // [NBC][XPAD]
  unsigned* acr    = (unsigned*)(pool + 4928);         // [64]
  unsigned* relr   = (unsigned*)(pool + 5184);         // [16]
  float*    x_lds  = (float*)(pool + 5248);            // conv fallback only

  const int lid   = threadIdx.x;
  const int c16   = lid & 15;
  const int q     = lid >> 4;
  const float rowm = (q & 1) ? 0.f : 1.f;   // rows 0,2: BCN; rows 1,3: LNR
  const int blk   = blockIdx.x;
  const int b     = blk >> 5;            // batch
  const int p     = blk & 31;            // chunk pair
  const int t0A   = p * (2 * CHC);
  const int t_begin = t0A - WU;

  if constexpr (PRECONV) {
    const __half* src = xfg + (size_t)b * NBC * TT;
    if (p == 0) {
      for (int e = lid; e < NBC * SPAN; e += 64) {
        int c = e / SPAN, i = e - c * SPAN;
        int gt = t_begin + i; if (gt < 0) gt = 0;   // chain-A warm garbage, reset later
        xf_lds[c * XPAD + i] = src[(size_t)c * TT + gt];
      }
    } else {
      for (int c = 0; c < NBC; ++c) {
        if (lid < SPAN / 4) {
          uint2 v = *(const uint2*)(src + (size_t)c * TT + t_begin + 4 * lid);
          *(uint2*)&xf_lds[c * XPAD + 4 * lid] = v;
        }
      }
    }
  } else {
    for (int i = lid; i < SPAN + KF - 1; i += 64) {
      int gt = t_begin - (KF - 1) + i;
      x_lds[i] = (gt >= 0) ? x[b * TT + gt] : 0.f;
    }
    __syncthreads();
    for (int ib = 0; ib < 3; ++ib) {
      int tau = lid + (ib << 6);
      if (tau < SPAN) {
        float acc[NBC];
#pragma unroll
        for (int c = 0; c < NBC; ++c) acc[c] = 0.f;
#pragma unroll 4
        for (int k = 0; k < KF; ++k) {
          float xv = x_lds[tau + k];
#pragma unroll
          for (int c = 0; c < NBC; ++c) acc[c] = fmaf(bck[c * KF + k], xv, acc[c]);
        }
#pragma unroll
        for (int c = 0; c < NBC; ++c) xf_lds[c * XPAD + tau] = __float2half(acc[c]);
      }
    }
    __syncthreads();
  }

  // ---- zero acr + relr ----
  if (lid < 64) acr[lid] = 0u;
  if (lid < 16) relr[lid] = 0u;

  // ---- per-lane parameters ----
  float slope2 = 0.f, soff2 = 0.f, osc_c = 0.f;
  f2 poolP; poolP.x = 1.f; poolP.y = 1.f;
  f2 SA; SA.x = 0.f; SA.y = 0.f;      // (S1,S2) chain A — infinite-history states
  f2 SB; SB.x = 0.f; SB.y = 0.f;
  f2 rv2, cn2; rv2.x = rv2.y = cn2.x = cn2.y = 0.f;
  float Adrv2 = 0.f, Boff2 = 0.f;
  __half2 wfbh[16];
  __half2 wuh[NBC];
  f2 yst[8], fst[8];                  // register output staging (8 steps)
  unsigned acst[8];

#pragma unroll
  for (int j = 0; j < 16; ++j) wfbh[j] = pk2(0.f, 0.f);
#pragma unroll
  for (int c = 0; c < NBC; ++c) wuh[c] = pk2(0.f, 0.f);

  if (c16 < NBC) {
    float sl = expf(lss[c16]);
    slope2 = sl * LOG2E;
    soff2  = soff[c16] * sl * LOG2E;
    osc_c  = oscale[c16];
#pragma unroll
    for (int j = 0; j < 16; ++j) {
      int a = 16 * q + j;
      if (a < NAC) { float w = -expf(labw[c16 * NAC + a]); wfbh[j] = pk2(w, w); }
    }
  }
  if (lid < NAC) {
    float tr = expf(ltr[lid]);
    float td = expf(ltd[lid]);
    float a1 = 1.f / td;
    float gg = (td + tr) / (td * tr);
    rv2.x = expf(-a1 * 0.015625f);  rv2.y = expf(-gg * 0.015625f);
    cn2.x = expf(-a1 * 0.003125f);  cn2.y = expf(-gg * 0.003125f);
    float nrm = 0.f;
    for (int k = 0; k < KF; ++k) {
      float kt = 0.8f - (float)k * 0.015625f;
      float d = expf(-a1 * kt) - expf(-gg * kt);
      nrm = fmaf(d, d, nrm);
    }
    float inorm  = 1.f / sqrtf(nrm);
    float aslope = expf(lass[lid]);
    Adrv2 = aslope * inorm * LOG2E;
    Boff2 = aslope * asoff[lid] * LOG2E;
#pragma unroll
    for (int c = 0; c < NBC; ++c) {
      float w = expf(lbaw[lid * NBC + c]);
      wuh[c] = pk2(w, w);
    }
  }

  float* yb  = out;
  float* fbp = out + (size_t)BB * TT * NBC;
  float* acp = out + 2 * (size_t)BB * TT * NBC;
  float* ylp = out + 2 * (size_t)BB * TT * NBC + (size_t)BB * TT * NAC;

  __syncthreads();

  auto step = [&](int slot, float xfA, float xfB, bool emit)
      __attribute__((always_inline)) {
    float mzA = fmaf(-Adrv2, SA.x - SA.y, Boff2);
    float mzB = fmaf(-Adrv2, SB.x - SB.y, Boff2);
    float acA = __fdividef(1.f, 1.f + exp2_f(mzA));
    float acB = __fdividef(1.f, 1.f + exp2_f(mzB));
    if (lid < NAC) acr[lid] = bcu(pk2(acA, acB));

    // fb[c16]: row partial over 16 packed ACs -> 4 b128 + 16 v_pk_fma_f16
    const uint4* ab = (const uint4*)(acr + (q << 4));
    uint4 A0 = ab[0], A1 = ab[1], A2 = ab[2], A3 = ab[3];
    __half2 g0 = __hmul2(wfbh[0], bch(A0.x));
    __half2 g1 = __hmul2(wfbh[1], bch(A0.y));
    g0 = __hfma2(wfbh[2],  bch(A0.z), g0);  g1 = __hfma2(wfbh[3],  bch(A0.w), g1);
    g0 = __hfma2(wfbh[4],  bch(A1.x), g0);  g1 = __hfma2(wfbh[5],  bch(A1.y), g1);
    g0 = __hfma2(wfbh[6],  bch(A1.z), g0);  g1 = __hfma2(wfbh[7],  bch(A1.w), g1);
    g0 = __hfma2(wfbh[8],  bch(A2.x), g0);  g1 = __hfma2(wfbh[9],  bch(A2.y), g1);
    g0 = __hfma2(wfbh[10], bch(A2.z), g0);  g1 = __hfma2(wfbh[11], bch(A2.w), g1);
    g0 = __hfma2(wfbh[12], bch(A3.x), g0);  g1 = __hfma2(wfbh[13], bch(A3.y), g1);
    g0 = __hfma2(wfbh[14], bch(A3.z), g0);  g1 = __hfma2(wfbh[15], bch(A3.w), g1);
    __half2 gs = xsum32h(xsum16h(__hadd2(g0, g1)));
    float fbA = __low2float(gs), fbB = __high2float(gs);

    float mA = fmaf(-slope2, fmaf(rowm, fbA, xfA), soff2);
    float mB = fmaf(-slope2, fmaf(rowm, fbB, xfB), soff2);
    f2 pv;
    pv.x = __fdividef(1.f, 1.f + exp2_f(mA));
    pv.y = __fdividef(1.f, 1.f + exp2_f(mB));
    f2 p2 = poolP * (1.f - RHO) + RHO;
    f2 relP = pv * p2;
    poolP = p2 - relP;
    if (lid < NBC) relr[lid] = bcu(pk2(relP.x, relP.y));
    if (emit) {
      yst[slot] = relP * osc_c;
      f2 t; t.x = fbA; t.y = fbB; fst[slot] = t;
      acst[slot] = bcu(pk2(acA, acB));
    }

    // u[lid]: 4 b128 broadcast reads + 14 v_pk_fma_f16
    const uint4* rb = (const uint4*)relr;
    uint4 R0 = rb[0], R1 = rb[1], R2 = rb[2], R3 = rb[3];
    __half2 h0 = __hmul2(wuh[0], bch(R0.x));
    __half2 h1 = __hmul2(wuh[1], bch(R0.y));
    h0 = __hfma2(wuh[2],  bch(R0.z), h0);  h1 = __hfma2(wuh[3],  bch(R0.w), h1);
    h0 = __hfma2(wuh[4],  bch(R1.x), h0);  h1 = __hfma2(wuh[5],  bch(R1.y), h1);
    h0 = __hfma2(wuh[6],  bch(R1.z), h0);  h1 = __hfma2(wuh[7],  bch(R1.w), h1);
    h0 = __hfma2(wuh[8],  bch(R2.x), h0);  h1 = __hfma2(wuh[9],  bch(R2.y), h1);
    h0 = __hfma2(wuh[10], bch(R2.z), h0);  h1 = __hfma2(wuh[11], bch(R2.w), h1);
    h0 = __hfma2(wuh[12], bch(R3.x), h0);  h1 = __hfma2(wuh[13], bch(R3.y), h1);
    __half2 uh = __hadd2(h0, h1);
    // infinite-history exponential states (tail beyond kt=0.8 is <=3e-4 in ac)
    SA = SA * rv2 + cn2 * __low2float(uh);
    SB = SB * rv2 + cn2 * __high2float(uh);
  };

  auto group = [&](int s4, int slotbase, bool emit) __attribute__((always_inline)) {
    uint2 xa = *(const uint2*)&xf_lds[c16 * XPAD + s4];
    uint2 xb = *(const uint2*)&xf_lds[c16 * XPAD + s4 + CHC];
    __half2 xA01 = bch(xa.x), xA23 = bch(xa.y);
    __half2 xB01 = bch(xb.x), xB23 = bch(xb.y);
    step(slotbase + 0, __low2float(xA01),  __low2float(xB01),  emit);
    step(slotbase + 1, __high2float(xA01), __high2float(xB01), emit);
    step(slotbase + 2, __low2float(xA23),  __low2float(xB23),  emit);
    step(slotbase + 3, __high2float(xA23), __high2float(xB23), emit);
  };

  // ---- warm phase ----
  for (int s4 = 0; s4 < WU; s4 += 4) group(s4, 0, false);

  // chunk-0 exact start: reset chain A state (true history is empty)
  if (p == 0) {
    SA.x = 0.f; SA.y = 0.f;
    poolP.x = 1.f;
  }

  // ---- emit phase: 8 steps per flush ----
  for (int s8 = WU; s8 < NTW; s8 += 8) {
    group(s8, 0, true);
    group(s8 + 4, 4, true);

    int tg = t0A + (s8 - WU);
    size_t base = (size_t)b * TT + tg;
    if (lid < NBC) {                       // row 0: y_bcn + fb
      size_t ob = base * NBC + lid;
#pragma unroll
      for (int sl = 0; sl < 8; ++sl) {
        yb [ob + sl * NBC]                     = yst[sl].x;
        yb [ob + (size_t)CHC * NBC + sl * NBC] = yst[sl].y;
        fbp[ob + sl * NBC]                     = fst[sl].x;
        fbp[ob + (size_t)CHC * NBC + sl * NBC] = fst[sl].y;
      }
    } else if (lid >= 16 && lid < 16 + NBC) {  // row 1: y_lnr
      size_t ob = base * NBC + (lid - 16);
#pragma unroll
      for (int sl = 0; sl < 8; ++sl) {
        ylp[ob + sl * NBC]                     = yst[sl].x;
        ylp[ob + (size_t)CHC * NBC + sl * NBC] = yst[sl].y;
      }
    }
    if (lid < NAC) {
      size_t oa = base * NAC + lid;
#pragma unroll
      for (int sl = 0; sl < 8; ++sl) {
        __half2 h = bch(acst[sl]);
        acp[oa + sl * NAC]                     = __low2float(h);
        acp[oa + (size_t)CHC * NAC + sl * NAC] = __high2float(h);
      }
    }
  }
}

extern "C" void kernel_launch(void* const* d_in, const int* in_sizes, int n_in,
                              void* d_out, int out_size, void* d_ws, size_t ws_size,
                              hipStream_t stream) {
  (void)in_sizes; (void)n_in; (void)out_size;
  const float* x    = (const float*)d_in[0];
  const float* bck  = (const float*)d_in[1];
  if (ws_size >= XF_BYTES) {
    __half* xfg = (__half*)d_ws;
    conv_kernel<<<dim3(BB * 16), dim3(256), 0, stream>>>(x, bck, xfg);
    bcn_kernel<true><<<dim3(BB * NPAIR), dim3(64), 0, stream>>>(
        x, bck, (const float*)d_in[2], (const float*)d_in[3], (const float*)d_in[4],
        (const float*)d_in[5], (const float*)d_in[6], (const float*)d_in[7],
        (const float*)d_in[8], (const float*)d_in[9], (const float*)d_in[10],
        xfg, (float*)d_out);
  } else {
    bcn_kernel<false><<<dim3(BB * NPAIR), dim3(64), 0, stream>>>(
        x, bck, (const float*)d_in[2], (const float*)d_in[3], (const float*)d_in[4],
        (const float*)d_in[5], (const float*)d_in[6], (const float*)d_in[7],
        (const float*)d_in[8], (const float*)d_in[9], (const float*)d_in[10],
        (const __half*)nullptr, (float*)d_out);
  }
}